// Round 6
// baseline (680.458 us; speedup 1.0000x reference)
//
#include <hip/hip_runtime.h>
#include <hip/hip_bf16.h>

// EGNN encoder, N=50000, E=250000, D=128, L=4. bf16 inputs/output (verified R2).
// R3: CSR-by-tgt aggregation (no atomics), fused A/B matmul, EW2@NW1b folding.
// R4: 3-stage parallel CSR scan.
// R5: agg_kernel chunked x4, v_rcp_f32, scalarized CSR loads.
// R6: per-layer mega-fusion: hidden-mm + residual-mm + next-layer A/B mm (or
//     final layernorm) in ONE kernel via wave-private LDS C->A relayout.
//     Kills hb round-trip, per-layer mmab, and ln_kernel.

#define NNODES 50000
#define NEDGES 250000

typedef unsigned short u16;
typedef __attribute__((ext_vector_type(8))) short bf16x8;
typedef __attribute__((ext_vector_type(4))) float floatx4;

__device__ __forceinline__ float b2f(u16 h){ unsigned u=((unsigned)h)<<16; float f; __builtin_memcpy(&f,&u,4); return f; }
__device__ __forceinline__ u16 f2b(float f){ unsigned u; __builtin_memcpy(&u,&f,4); u = u + 0x7FFFu + ((u>>16)&1u); return (u16)(u>>16); }
// fast silu: v_exp + v_rcp (1 ulp), fine vs 2%-of-absmax threshold
__device__ __forceinline__ float siluf(float x){ return x*__builtin_amdgcn_rcpf(1.f+__expf(-x)); }
__device__ __forceinline__ float ldf(const void* p, long i, int isbf){
  return isbf ? b2f(((const u16*)p)[i]) : ((const float*)p)[i];
}

__global__ void detect_kernel(const void* lng, int* flag){
  if (threadIdx.x==0 && blockIdx.x==0) *flag = (((const u16*)lng)[0] != 0) ? 1 : 0;
}

// ---------- weight packing into MFMA B-fragment order (24 input matrices) ----------
__global__ __launch_bounds__(256) void pack_kernel(
    const void* __restrict__ ew1, const void* __restrict__ ew2,
    const void* __restrict__ nw1, const void* __restrict__ nw2,
    u16* __restrict__ packed, const int* __restrict__ flagp)
{
  const int isbf = *flagp;
  int t = blockIdx.x*256 + threadIdx.x;       // 24 * 2048
  int m = t >> 11; int r = t & 2047;
  int lane = r & 63; int ntk = r >> 6;
  int kk = ntk >> 3, nt = ntk & 7;
  int l = m/6, w = m%6;
  const void* src; long off;
  switch(w){
    case 0: src=ew1; off=(long)l*257*128;            break; // W1a
    case 1: src=ew1; off=(long)l*257*128 + 128*128;  break; // W1b
    case 2: src=ew2; off=(long)l*128*128;            break; // EW2
    case 3: src=nw1; off=(long)l*256*128;            break; // NW1a
    case 4: src=nw1; off=(long)l*256*128 + 128*128;  break; // NW1b
    default:src=nw2; off=(long)l*128*128;            break; // NW2
  }
  int c  = nt*16 + (lane & 15);
  int k0 = kk*32 + (lane >> 4)*8;
  u16 vals[8];
#pragma unroll
  for (int j=0;j<8;j++){
    long idx = off + (long)(k0+j)*128 + c;
    vals[j] = isbf ? ((const u16*)src)[idx] : f2b(((const float*)src)[idx]);
  }
  bf16x8 v; __builtin_memcpy(&v, vals, 16);
  *(bf16x8*)(packed + (long)t*8) = v;
}

// ---------- pack fp32 W12[l] (4 matrices) into chunks 24..27 ----------
__global__ __launch_bounds__(256) void pack2_kernel(
    const float* __restrict__ W12f, u16* __restrict__ packed)
{
  int t = blockIdx.x*256 + threadIdx.x;       // 4 * 2048
  int m = t >> 11; int r = t & 2047;
  int lane = r & 63; int ntk = r >> 6;
  int kk = ntk >> 3, nt = ntk & 7;
  const float* base = W12f + (long)m*16384;
  int c  = nt*16 + (lane & 15);
  int k0 = kk*32 + (lane >> 4)*8;
  u16 vals[8];
#pragma unroll
  for (int j=0;j<8;j++) vals[j] = f2b(base[(long)(k0+j)*128 + c]);
  bf16x8 v; __builtin_memcpy(&v, vals, 16);
  *(bf16x8*)(packed + ((long)(24+m)*2048 + r)*8) = v;
}

// ---------- W12[l][k][j] = sum_d EW2[l][k][d]*NW1b[l][d][j] (fp32) ----------
__global__ __launch_bounds__(128) void w12_kernel(
    const void* __restrict__ ew2, const void* __restrict__ nw1,
    float* __restrict__ W12f, const int* __restrict__ flagp)
{
  const int isbf = *flagp;
  int l = blockIdx.x >> 7, k = blockIdx.x & 127, j = threadIdx.x;
  long e2 = (long)l*16384 + (long)k*128;
  long nb = (long)l*256*128 + 128*128;
  float acc = 0.f;
  for (int d=0; d<128; d++)
    acc += ldf(ew2, e2 + d, isbf) * ldf(nw1, nb + (long)d*128 + j, isbf);
  W12f[(long)l*16384 + (long)k*128 + j] = acc;
}

// ---------- ebW[l][j] = sum_d eb2[l][d]*NW1b[l][d][j] ----------
__global__ __launch_bounds__(128) void ebw_kernel(
    const void* __restrict__ eb2, const void* __restrict__ nw1,
    float* __restrict__ ebW, const int* __restrict__ flagp)
{
  const int isbf = *flagp;
  int l = blockIdx.x, j = threadIdx.x;
  long nb = (long)l*256*128 + 128*128;
  float acc = 0.f;
  for (int d=0; d<128; d++)
    acc += ldf(eb2, (long)l*128 + d, isbf) * ldf(nw1, nb + (long)d*128 + j, isbf);
  ebW[l*128+j] = acc;
}

// ---------- per-layer w2p = EW2 @ pw1[0:128], c2p = eb2 . pw1[0:128] ----------
__global__ __launch_bounds__(128) void w2p_kernel(
    const void* __restrict__ ew2, const void* __restrict__ eb2, const void* __restrict__ pw1,
    float* __restrict__ w2p, float* __restrict__ c2p, const int* __restrict__ flagp)
{
  const int isbf = *flagp;
  int l = blockIdx.x, i = threadIdx.x;
  long Woff = (long)l*128*128, poff = (long)l*129;
  float acc = 0.f;
  for (int j=0;j<128;j++) acc += ldf(ew2, Woff + (long)i*128 + j, isbf) * ldf(pw1, poff + j, isbf);
  w2p[l*128+i] = acc;
  __shared__ float red[128];
  red[i] = ldf(eb2, (long)l*128 + i, isbf) * ldf(pw1, poff + i, isbf);
  __syncthreads();
  for (int st=64; st>0; st>>=1){ if (i<st) red[i]+=red[i+st]; __syncthreads(); }
  if (i==0) c2p[l] = red[0];
}

__global__ void pparm_kernel(const void* pw1, const void* pb1, const void* pw2, const void* pb2,
                             float* pparm, const int* flagp)
{
  const int isbf = *flagp;
  int l = threadIdx.x;
  if (l < 4){
    pparm[l*4+0] = ldf(pw1, (long)l*129 + 128, isbf);
    pparm[l*4+1] = ldf(pb1, l, isbf);
    pparm[l*4+2] = ldf(pw2, l, isbf);
    pparm[l*4+3] = ldf(pb2, l, isbf);
  }
}

// ---------- CSR build: histogram, 3-stage scan, scatter ----------
__global__ __launch_bounds__(256) void hist_kernel(const int* __restrict__ tgt, int* __restrict__ cnt, int E){
  int i = blockIdx.x*256 + threadIdx.x;
  if (i < E) atomicAdd(&cnt[tgt[i]], 1);
}

__global__ __launch_bounds__(256) void bsum_kernel(const int* __restrict__ cnt, int* __restrict__ bsum, int N){
  int i = blockIdx.x*256 + threadIdx.x;
  int v = (i < N) ? cnt[i] : 0;
#pragma unroll
  for (int off=32; off; off>>=1) v += __shfl_down(v, off);
  __shared__ int ws[4];
  if ((threadIdx.x & 63) == 0) ws[threadIdx.x>>6] = v;
  __syncthreads();
  if (threadIdx.x == 0) bsum[blockIdx.x] = ws[0]+ws[1]+ws[2]+ws[3];
}

__global__ __launch_bounds__(256) void bscan_kernel(int* __restrict__ bsum, int nb){
  __shared__ int lds[256];
  int i = threadIdx.x;
  int v = (i < nb) ? bsum[i] : 0;
  lds[i] = v; __syncthreads();
#pragma unroll
  for (int off=1; off<256; off<<=1){
    int t = (i>=off)? lds[i-off] : 0; __syncthreads();
    lds[i] += t; __syncthreads();
  }
  if (i < nb) bsum[i] = lds[i] - v;  // exclusive prefix
}

__global__ __launch_bounds__(256) void csr_kernel(
    const int* __restrict__ cnt, const int* __restrict__ bsum,
    int* __restrict__ rowptr, int* __restrict__ cursor, float* __restrict__ degf, int N)
{
  __shared__ int lds[256];
  int i = blockIdx.x*256 + threadIdx.x;
  int c = (i < N) ? cnt[i] : 0;
  lds[threadIdx.x] = c; __syncthreads();
#pragma unroll
  for (int off=1; off<256; off<<=1){
    int t = (threadIdx.x>=off)? lds[threadIdx.x-off] : 0; __syncthreads();
    lds[threadIdx.x] += t; __syncthreads();
  }
  int run = bsum[blockIdx.x] + lds[threadIdx.x] - c;  // exclusive
  if (i < N){
    rowptr[i] = run; cursor[i] = run; degf[i] = (float)c;
    if (i == N-1) rowptr[N] = run + c;
  }
}

__global__ __launch_bounds__(256) void scatter_kernel(
    const int* __restrict__ src, const int* __restrict__ tgt,
    int* __restrict__ cursor, int* __restrict__ permsrc, int E)
{
  int e = blockIdx.x*256 + threadIdx.x;
  if (e >= E) return;
  int t = tgt[e];
  int p = atomicAdd(&cursor[t], 1);
  permsrc[p] = src[e];
}

// ---------- initial projection x = nf @ npw + npb (2 nodes/block) ----------
__global__ __launch_bounds__(256) void proj_kernel(
    const void* __restrict__ nf, const void* __restrict__ W, const void* __restrict__ bvec,
    float* __restrict__ xf, u16* __restrict__ xb, int N, const int* __restrict__ flagp)
{
  const int isbf = *flagp;
  int n = blockIdx.x*2 + (threadIdx.x>>7), d = threadIdx.x & 127;
  if (n >= N) return;
  float acc = ldf(bvec, d, isbf);
#pragma unroll
  for (int f=0; f<12; f++) acc += ldf(nf, (long)n*12+f, isbf) * ldf(W, f*128+d, isbf);
  xf[(long)n*128+d] = acc;
  xb[(long)n*128+d] = f2b(acc);
}

__global__ __launch_bounds__(256) void cvtp_kernel(const void* __restrict__ pos, float* __restrict__ pf,
                                                   int n, const int* __restrict__ flagp){
  const int isbf = *flagp;
  int i = blockIdx.x*256 + threadIdx.x;
  if (i < n) pf[i] = ldf(pos, i, isbf);
}

// ---------- layer-0 A/B matmul: Ab = bf16(x@W1a+eb1), Bb = bf16(x@W1b) ----------
__global__ __launch_bounds__(256) void mmab_kernel(
    const u16* __restrict__ X, const u16* __restrict__ Wa, const u16* __restrict__ Wb,
    const void* __restrict__ bias, long bias_off,
    u16* __restrict__ Ab, u16* __restrict__ Bb, int nrows, const int* __restrict__ flagp)
{
  const int tid = threadIdx.x;
  const int wave = tid>>6, lane = tid&63;
  const int row0 = (blockIdx.x*4 + wave)*16;
  if (row0 >= nrows) return;
  const int isbf = *flagp;
  const int lr = lane&15, lg = lane>>4;
  floatx4 accA[8], accB[8];
#pragma unroll
  for (int i=0;i<8;i++){ accA[i]=(floatx4){0,0,0,0}; accB[i]=(floatx4){0,0,0,0}; }
  int arow = row0 + lr; if (arow >= nrows) arow = nrows-1;
  const u16* xr = X + (long)arow*128;
#pragma unroll
  for (int kk=0;kk<4;kk++){
    bf16x8 a = *(const bf16x8*)(xr + kk*32 + lg*8);
#pragma unroll
    for (int nt=0;nt<8;nt++){
      bf16x8 ba = *(const bf16x8*)(Wa + ((kk*8+nt)*64 + lane)*8);
      accA[nt] = __builtin_amdgcn_mfma_f32_16x16x32_bf16(a, ba, accA[nt], 0, 0, 0);
      bf16x8 bb = *(const bf16x8*)(Wb + ((kk*8+nt)*64 + lane)*8);
      accB[nt] = __builtin_amdgcn_mfma_f32_16x16x32_bf16(a, bb, accB[nt], 0, 0, 0);
    }
  }
#pragma unroll
  for (int r=0;r<4;r++){
    int row = row0 + lg*4 + r;
    if (row >= nrows) continue;
#pragma unroll
    for (int nt=0;nt<8;nt++){
      int col = nt*16 + lr;
      Ab[(long)row*128+col] = f2b(accA[nt][r] + ldf(bias, bias_off + col, isbf));
      Bb[(long)row*128+col] = f2b(accB[nt][r]);
    }
  }
}

// ---------- fused per-layer node update ----------
// hidden = silu(xb@NW1a + Hb@W12 + deg*ebW + nb1)        (MFMA x2, C-layout)
//   -> wave-private LDS (bf16, 16x136)  [C->A relayout, no barrier]
// xnew = xf + hidden@NW2 + nb2                            (MFMA)
// AB=1:  Ab = xnew@W1an + eb1n, Bb = xnew@W1bn  (next layer, via LDS relayout)
// LNORM=1: layernorm(xnew)*g+b -> out  (row stats via shfl in 16-lane groups)
template<int AB, int LNORM>
__global__ __launch_bounds__(256) void fused_kernel(
    const u16* __restrict__ xb, const u16* __restrict__ Hb,
    const u16* __restrict__ NW1a, const u16* __restrict__ W12p, const u16* __restrict__ NW2p,
    const u16* __restrict__ W1an, const u16* __restrict__ W1bn,
    const void* __restrict__ nb1, long nb1_off,
    const void* __restrict__ nb2, long nb2_off,
    const void* __restrict__ eb1n, long eb1_off,
    const float* __restrict__ degf, const float* __restrict__ ebW,
    float* __restrict__ xf, u16* __restrict__ xb_out,
    u16* __restrict__ Ab, u16* __restrict__ Bb,
    const void* __restrict__ lng, const void* __restrict__ lnb, void* __restrict__ outp,
    int nrows, const int* __restrict__ flagp)
{
  __shared__ u16 lds[4][16*136];
  const int tid = threadIdx.x;
  const int wave = tid>>6, lane = tid&63;
  const int row0 = (blockIdx.x*4 + wave)*16;
  if (row0 >= nrows) return;
  const int isbf = *flagp;
  const int lr = lane&15, lg = lane>>4;
  u16* ldsw = &lds[wave][0];

  floatx4 acc[8];
#pragma unroll
  for (int i=0;i<8;i++) acc[i] = (floatx4){0.f,0.f,0.f,0.f};
  int arow = row0 + lr; if (arow >= nrows) arow = nrows-1;
  // MFMA1a: xb @ NW1a
  {
    const u16* xr = xb + (long)arow*128;
#pragma unroll
    for (int kk=0;kk<4;kk++){
      bf16x8 a = *(const bf16x8*)(xr + kk*32 + lg*8);
#pragma unroll
      for (int nt=0;nt<8;nt++){
        bf16x8 b = *(const bf16x8*)(NW1a + ((kk*8+nt)*64 + lane)*8);
        acc[nt] = __builtin_amdgcn_mfma_f32_16x16x32_bf16(a, b, acc[nt], 0, 0, 0);
      }
    }
  }
  // MFMA1b: Hb @ W12
  {
    const u16* hr = Hb + (long)arow*128;
#pragma unroll
    for (int kk=0;kk<4;kk++){
      bf16x8 a = *(const bf16x8*)(hr + kk*32 + lg*8);
#pragma unroll
      for (int nt=0;nt<8;nt++){
        bf16x8 b = *(const bf16x8*)(W12p + ((kk*8+nt)*64 + lane)*8);
        acc[nt] = __builtin_amdgcn_mfma_f32_16x16x32_bf16(a, b, acc[nt], 0, 0, 0);
      }
    }
  }
  // epilogue1: bias + deg term + silu -> LDS (bf16 hidden, 16x136)
  float dv[4];
#pragma unroll
  for (int r=0;r<4;r++){ int row=row0+lg*4+r; if(row>=nrows) row=nrows-1; dv[r]=degf[row]; }
  float nb1v[8], ebv[8];
#pragma unroll
  for (int nt=0;nt<8;nt++){ int col=nt*16+lr; nb1v[nt]=ldf(nb1, nb1_off+col, isbf); ebv[nt]=ebW[col]; }
#pragma unroll
  for (int r=0;r<4;r++){
#pragma unroll
    for (int nt=0;nt<8;nt++){
      int col = nt*16 + lr;
      float v = acc[nt][r] + nb1v[nt] + dv[r]*ebv[nt];
      ldsw[(lg*4+r)*136 + col] = f2b(siluf(v));
    }
  }
  // MFMA2: hidden @ NW2 (a-frags from LDS)
#pragma unroll
  for (int i=0;i<8;i++) acc[i] = (floatx4){0.f,0.f,0.f,0.f};
#pragma unroll
  for (int kk=0;kk<4;kk++){
    bf16x8 a = *(const bf16x8*)(ldsw + lr*136 + kk*32 + lg*8);
#pragma unroll
    for (int nt=0;nt<8;nt++){
      bf16x8 b = *(const bf16x8*)(NW2p + ((kk*8+nt)*64 + lane)*8);
      acc[nt] = __builtin_amdgcn_mfma_f32_16x16x32_bf16(a, b, acc[nt], 0, 0, 0);
    }
  }
  // epilogue2: residual add
  float nb2v[8];
#pragma unroll
  for (int nt=0;nt<8;nt++) nb2v[nt] = ldf(nb2, nb2_off + nt*16+lr, isbf);
#pragma unroll
  for (int r=0;r<4;r++){
    int row = row0 + lg*4 + r;
    int ok = row < nrows;
    long rowc = ok ? row : (nrows-1);
#pragma unroll
    for (int nt=0;nt<8;nt++){
      int col = nt*16 + lr;
      float v = acc[nt][r] + nb2v[nt] + xf[rowc*128+col];
      if (LNORM){
        acc[nt][r] = v;
      } else {
        u16 hv = f2b(v);
        if (ok){ xf[rowc*128+col] = v; xb_out[rowc*128+col] = hv; }
        if (AB) ldsw[(lg*4+r)*136 + col] = hv;
      }
    }
  }
  if (AB){
    // MFMA3: xnew @ W1an / W1bn (next layer A/B), a-frags from LDS
    floatx4 aA[8], aB[8];
#pragma unroll
    for (int i=0;i<8;i++){ aA[i]=(floatx4){0,0,0,0}; aB[i]=(floatx4){0,0,0,0}; }
#pragma unroll
    for (int kk=0;kk<4;kk++){
      bf16x8 a = *(const bf16x8*)(ldsw + lr*136 + kk*32 + lg*8);
#pragma unroll
      for (int nt=0;nt<8;nt++){
        bf16x8 ba = *(const bf16x8*)(W1an + ((kk*8+nt)*64 + lane)*8);
        aA[nt] = __builtin_amdgcn_mfma_f32_16x16x32_bf16(a, ba, aA[nt], 0, 0, 0);
        bf16x8 bb = *(const bf16x8*)(W1bn + ((kk*8+nt)*64 + lane)*8);
        aB[nt] = __builtin_amdgcn_mfma_f32_16x16x32_bf16(a, bb, aB[nt], 0, 0, 0);
      }
    }
    float e1v[8];
#pragma unroll
    for (int nt=0;nt<8;nt++) e1v[nt] = ldf(eb1n, eb1_off + nt*16+lr, isbf);
#pragma unroll
    for (int r=0;r<4;r++){
      int row = row0 + lg*4 + r;
      if (row >= nrows) continue;
#pragma unroll
      for (int nt=0;nt<8;nt++){
        int col = nt*16 + lr;
        Ab[(long)row*128+col] = f2b(aA[nt][r] + e1v[nt]);
        Bb[(long)row*128+col] = f2b(aB[nt][r]);
      }
    }
  }
  if (LNORM){
    float s[4] = {0,0,0,0}, q[4] = {0,0,0,0};
#pragma unroll
    for (int r=0;r<4;r++){
#pragma unroll
      for (int nt=0;nt<8;nt++){ float v = acc[nt][r]; s[r] += v; q[r] += v*v; }
    }
#pragma unroll
    for (int mask=1; mask<16; mask<<=1){
#pragma unroll
      for (int r=0;r<4;r++){ s[r] += __shfl_xor(s[r], mask); q[r] += __shfl_xor(q[r], mask); }
    }
    float muv[4], invv[4];
#pragma unroll
    for (int r=0;r<4;r++){
      float mu = s[r]*(1.f/128.f);
      float var = q[r]*(1.f/128.f) - mu*mu;
      muv[r] = mu; invv[r] = rsqrtf(var + 1e-5f);
    }
    float gv[8], bvv[8];
#pragma unroll
    for (int nt=0;nt<8;nt++){ int col=nt*16+lr; gv[nt]=ldf(lng,col,isbf); bvv[nt]=ldf(lnb,col,isbf); }
#pragma unroll
    for (int r=0;r<4;r++){
      int row = row0 + lg*4 + r;
      if (row >= nrows) continue;
#pragma unroll
      for (int nt=0;nt<8;nt++){
        int col = nt*16 + lr;
        float y = (acc[nt][r]-muv[r])*invv[r]*gv[nt] + bvv[nt];
        if (isbf) ((u16*)outp)[(long)row*128+col] = f2b(y);
        else      ((float*)outp)[(long)row*128+col] = y;
      }
    }
  }
}

// ---------- CSR aggregation: one wave per target node, chunked x4 ----------
__global__ __launch_bounds__(256) void agg_kernel(
    const int* __restrict__ rowptr, const int* __restrict__ permsrc,
    const float* __restrict__ pf_in,
    const u16* __restrict__ A, const u16* __restrict__ B,
    const void* __restrict__ ew1, long w1c_off,
    const float* __restrict__ w2p, const float* __restrict__ c2pl,
    const float* __restrict__ pp,
    u16* __restrict__ Hb, float* __restrict__ pf_out, int N,
    const int* __restrict__ flagp)
{
  const int isbf = *flagp;
  int tid = threadIdx.x, lane = tid & 63;
  int t = blockIdx.x*4 + (tid>>6);
  if (t >= N) return;
  int tu = __builtin_amdgcn_readfirstlane(t);   // wave-uniform -> scalar loads
  float c0 = ldf(ew1, w1c_off + 2*lane,     isbf);
  float c1 = ldf(ew1, w1c_off + 2*lane + 1, isbf);
  float2 wp = *(const float2*)(w2p + 2*lane);
  float c2 = c2pl[0];
  float p0 = pp[0], p1 = pp[1], p2 = pp[2], p3 = pp[3];
  int jb = rowptr[tu], je = rowptr[tu+1];
  float2 pt = *(const float2*)(pf_in + 2*(long)tu);
  unsigned bv = *(const unsigned*)(B + (long)tu*128 + 2*lane);
  float b0 = b2f((u16)bv), b1 = b2f((u16)(bv>>16));
  float h0a = 0.f, h1a = 0.f, dpx = 0.f, dpy = 0.f;
  for (int j0 = jb; j0 < je; j0 += 4){
    int m = je - j0; if (m > 4) m = 4;
    int s[4]; float2 ps[4]; unsigned av[4];
    float part[4], dist[4], dxv[4], dyv[4];
#pragma unroll
    for (int c=0;c<4;c++) if (c<m) s[c] = permsrc[j0+c];
#pragma unroll
    for (int c=0;c<4;c++) if (c<m){
      ps[c] = *(const float2*)(pf_in + 2*(long)s[c]);
      av[c] = *(const unsigned*)(A + (long)s[c]*128 + 2*lane);
    }
#pragma unroll
    for (int c=0;c<4;c++){
      if (c<m){
        float dx = pt.x - ps[c].x, dy = pt.y - ps[c].y;
        float d2 = dx*dx + dy*dy;
        float dd = __builtin_amdgcn_sqrtf(d2);
        float h0 = siluf(b2f((u16)av[c])       + b0 + dd*c0);
        float h1 = siluf(b2f((u16)(av[c]>>16)) + b1 + dd*c1);
        h0a += h0; h1a += h1;
        part[c] = h0*wp.x + h1*wp.y;
        dist[c] = dd; dxv[c] = dx; dyv[c] = dy;
      } else part[c] = 0.f;
    }
#pragma unroll
    for (int off=32; off; off>>=1){
#pragma unroll
      for (int c=0;c<4;c++) part[c] += __shfl_xor(part[c], off);
    }
#pragma unroll
    for (int c=0;c<4;c++){
      if (c<m){
        float spre = part[c] + c2 + dist[c]*p0 + p1;
        float pwv  = siluf(spre)*p2 + p3;
        float inv  = __builtin_amdgcn_rcpf(dist[c] + 1e-6f);
        dpx += dxv[c]*inv*pwv; dpy += dyv[c]*inv*pwv;
      }
    }
  }
  *(unsigned*)(Hb + (long)tu*128 + 2*lane) = (unsigned)f2b(h0a) | ((unsigned)f2b(h1a)<<16);
  if (lane == 0){
    float2 o; o.x = pt.x + dpx; o.y = pt.y + dpy;
    *(float2*)(pf_out + 2*(long)tu) = o;
  }
}

extern "C" void kernel_launch(void* const* d_in, const int* in_sizes, int n_in,
                              void* d_out, int out_size, void* d_ws, size_t ws_size,
                              hipStream_t stream)
{
  const void* nf  = d_in[0];
  const void* pos = d_in[1];
  const void* npw = d_in[3];
  const void* npb = d_in[4];
  const void* ew1 = d_in[7];
  const void* eb1 = d_in[8];
  const void* ew2 = d_in[9];
  const void* eb2 = d_in[10];
  const void* nw1 = d_in[11];
  const void* nb1 = d_in[12];
  const void* nw2 = d_in[13];
  const void* nb2 = d_in[14];
  const void* pw1 = d_in[15];
  const void* pb1 = d_in[16];
  const void* pw2 = d_in[17];
  const void* pb2 = d_in[18];
  const void* lng = d_in[19];
  const void* lnb = d_in[20];
  const int* eidx = (const int*)d_in[21];
  const int N = NNODES, E = NEDGES;
  const int* srcp = eidx;
  const int* tgtp = eidx + E;

  char* w = (char*)d_ws;
  size_t off = 0;
  auto alloc = [&](size_t bytes)->char* { char* p = w + off; off += (bytes + 255)/256*256; return p; };
  float* xf    = (float*)alloc((size_t)N*128*4);
  u16*   xb    = (u16*)  alloc((size_t)N*128*2);
  u16*   Ab    = (u16*)  alloc((size_t)N*128*2);
  u16*   Bb    = (u16*)  alloc((size_t)N*128*2);
  u16*   Hb    = (u16*)  alloc((size_t)N*128*2);
  float* pf0   = (float*)alloc((size_t)N*2*4);
  float* pf1   = (float*)alloc((size_t)N*2*4);
  int*   cnt   = (int*)  alloc((size_t)N*4);
  int*   rowptr= (int*)  alloc((size_t)(N+1)*4);
  int*   cursor= (int*)  alloc((size_t)N*4);
  float* degf  = (float*)alloc((size_t)N*4);
  int*   perm  = (int*)  alloc((size_t)E*4);
  int*   bsum  = (int*)  alloc(256*4);
  u16*   pk    = (u16*)  alloc((size_t)28*16384*2);
  float* W12f  = (float*)alloc((size_t)4*16384*4);
  float* ebW   = (float*)alloc(4*128*4);
  float* w2p   = (float*)alloc(4*128*4);
  float* c2p   = (float*)alloc(4*4);
  float* pparm = (float*)alloc(16*4);
  int*   flag  = (int*)  alloc(4);

  const int NB = (N + 255)/256;  // 196 <= 256
  detect_kernel<<<1, 64, 0, stream>>>(lng, flag);
  hipMemsetAsync(cnt, 0, (size_t)N*4, stream);
  hist_kernel<<<(E+255)/256, 256, 0, stream>>>(tgtp, cnt, E);
  bsum_kernel<<<NB, 256, 0, stream>>>(cnt, bsum, N);
  bscan_kernel<<<1, 256, 0, stream>>>(bsum, NB);
  csr_kernel<<<NB, 256, 0, stream>>>(cnt, bsum, rowptr, cursor, degf, N);
  scatter_kernel<<<(E+255)/256, 256, 0, stream>>>(srcp, tgtp, cursor, perm, E);
  pack_kernel<<<192, 256, 0, stream>>>(ew1, ew2, nw1, nw2, pk, flag);
  w12_kernel<<<512, 128, 0, stream>>>(ew2, nw1, W12f, flag);
  ebw_kernel<<<4, 128, 0, stream>>>(eb2, nw1, ebW, flag);
  pack2_kernel<<<32, 256, 0, stream>>>(W12f, pk);
  w2p_kernel<<<4, 128, 0, stream>>>(ew2, eb2, pw1, w2p, c2p, flag);
  pparm_kernel<<<1, 64, 0, stream>>>(pw1, pb1, pw2, pb2, pparm, flag);
  proj_kernel<<<(N+1)/2, 256, 0, stream>>>(nf, npw, npb, xf, xb, N, flag);
  cvtp_kernel<<<(2*N+255)/256, 256, 0, stream>>>(pos, pf0, 2*N, flag);

  const int GMM = (N + 63)/64;
  // layer 0 A/B from projected x
  mmab_kernel<<<GMM,256,0,stream>>>(xb, pk + 0*16384, pk + 1*16384, eb1, 0, Ab, Bb, N, flag);
  for (int l = 0; l < 4; l++){
    const u16* NW1a = pk + (l*6+3)*16384;
    const u16* NW2p = pk + (l*6+5)*16384;
    const u16* W12p = pk + (24+l)*16384;
    float* pin  = (l & 1) ? pf1 : pf0;
    float* pout = (l & 1) ? pf0 : pf1;

    agg_kernel<<<(N+3)/4, 256, 0, stream>>>(
        rowptr, perm, pin, Ab, Bb,
        ew1, (long)l*257*128 + 256*128,
        w2p + l*128, c2p + l, pparm + l*4,
        Hb, pout, N, flag);
    if (l < 3){
      const u16* W1an = pk + ((l+1)*6+0)*16384;
      const u16* W1bn = pk + ((l+1)*6+1)*16384;
      fused_kernel<1,0><<<GMM,256,0,stream>>>(
          xb, Hb, NW1a, W12p, NW2p, W1an, W1bn,
          nb1, (long)l*128, nb2, (long)l*128, eb1, (long)(l+1)*128,
          degf, ebW + l*128, xf, xb, Ab, Bb,
          nullptr, nullptr, nullptr, N, flag);
    } else {
      fused_kernel<0,1><<<GMM,256,0,stream>>>(
          xb, Hb, NW1a, W12p, NW2p, nullptr, nullptr,
          nb1, (long)l*128, nb2, (long)l*128, nullptr, 0,
          degf, ebW + l*128, xf, nullptr, nullptr, nullptr,
          lng, lnb, d_out, N, flag);
    }
  }
}

// Round 7
// 603.310 us; speedup vs baseline: 1.1279x; 1.1279x over previous
//
#include <hip/hip_runtime.h>
#include <hip/hip_bf16.h>

// EGNN encoder, N=50000, E=250000, D=128, L=4. bf16 inputs/output (verified R2).
// R3: CSR-by-tgt aggregation (no atomics), EW2@NW1b folding.
// R4: 3-stage parallel CSR scan.  R5: agg chunked x4 + fast rcp.
// R6: mega-fusion REGRESSED (latency-bound, MfmaUtil 3.8%) -> reverted.
// R7: weight-stationary streaming matmuls: weights staged in LDS once/block,
//     grid-stride over row tiles; layernorm fused into final res-matmul.

#define NNODES 50000
#define NEDGES 250000
#define NTILES 3125   // 50000/16 exactly, no tail
#define MMGRID 512

typedef unsigned short u16;
typedef __attribute__((ext_vector_type(8))) short bf16x8;
typedef __attribute__((ext_vector_type(4))) float floatx4;

__device__ __forceinline__ float b2f(u16 h){ unsigned u=((unsigned)h)<<16; float f; __builtin_memcpy(&f,&u,4); return f; }
__device__ __forceinline__ u16 f2b(float f){ unsigned u; __builtin_memcpy(&u,&f,4); u = u + 0x7FFFu + ((u>>16)&1u); return (u16)(u>>16); }
__device__ __forceinline__ float siluf(float x){ return x*__builtin_amdgcn_rcpf(1.f+__expf(-x)); }
__device__ __forceinline__ float ldf(const void* p, long i, int isbf){
  return isbf ? b2f(((const u16*)p)[i]) : ((const float*)p)[i];
}

__global__ void detect_kernel(const void* lng, int* flag){
  if (threadIdx.x==0 && blockIdx.x==0) *flag = (((const u16*)lng)[0] != 0) ? 1 : 0;
}

// ---------- weight packing into MFMA B-fragment order (24 input matrices) ----------
__global__ __launch_bounds__(256) void pack_kernel(
    const void* __restrict__ ew1, const void* __restrict__ ew2,
    const void* __restrict__ nw1, const void* __restrict__ nw2,
    u16* __restrict__ packed, const int* __restrict__ flagp)
{
  const int isbf = *flagp;
  int t = blockIdx.x*256 + threadIdx.x;       // 24 * 2048
  int m = t >> 11; int r = t & 2047;
  int lane = r & 63; int ntk = r >> 6;
  int kk = ntk >> 3, nt = ntk & 7;
  int l = m/6, w = m%6;
  const void* src; long off;
  switch(w){
    case 0: src=ew1; off=(long)l*257*128;            break; // W1a
    case 1: src=ew1; off=(long)l*257*128 + 128*128;  break; // W1b
    case 2: src=ew2; off=(long)l*128*128;            break; // EW2
    case 3: src=nw1; off=(long)l*256*128;            break; // NW1a
    case 4: src=nw1; off=(long)l*256*128 + 128*128;  break; // NW1b
    default:src=nw2; off=(long)l*128*128;            break; // NW2
  }
  int c  = nt*16 + (lane & 15);
  int k0 = kk*32 + (lane >> 4)*8;
  u16 vals[8];
#pragma unroll
  for (int j=0;j<8;j++){
    long idx = off + (long)(k0+j)*128 + c;
    vals[j] = isbf ? ((const u16*)src)[idx] : f2b(((const float*)src)[idx]);
  }
  bf16x8 v; __builtin_memcpy(&v, vals, 16);
  *(bf16x8*)(packed + (long)t*8) = v;
}

// ---------- pack fp32 W12[l] (4 matrices) into chunks 24..27 ----------
__global__ __launch_bounds__(256) void pack2_kernel(
    const float* __restrict__ W12f, u16* __restrict__ packed)
{
  int t = blockIdx.x*256 + threadIdx.x;       // 4 * 2048
  int m = t >> 11; int r = t & 2047;
  int lane = r & 63; int ntk = r >> 6;
  int kk = ntk >> 3, nt = ntk & 7;
  const float* base = W12f + (long)m*16384;
  int c  = nt*16 + (lane & 15);
  int k0 = kk*32 + (lane >> 4)*8;
  u16 vals[8];
#pragma unroll
  for (int j=0;j<8;j++) vals[j] = f2b(base[(long)(k0+j)*128 + c]);
  bf16x8 v; __builtin_memcpy(&v, vals, 16);
  *(bf16x8*)(packed + ((long)(24+m)*2048 + r)*8) = v;
}

// ---------- W12[l][k][j] = sum_d EW2[l][k][d]*NW1b[l][d][j] (fp32) ----------
__global__ __launch_bounds__(128) void w12_kernel(
    const void* __restrict__ ew2, const void* __restrict__ nw1,
    float* __restrict__ W12f, const int* __restrict__ flagp)
{
  const int isbf = *flagp;
  int l = blockIdx.x >> 7, k = blockIdx.x & 127, j = threadIdx.x;
  long e2 = (long)l*16384 + (long)k*128;
  long nb = (long)l*256*128 + 128*128;
  float acc = 0.f;
  for (int d=0; d<128; d++)
    acc += ldf(ew2, e2 + d, isbf) * ldf(nw1, nb + (long)d*128 + j, isbf);
  W12f[(long)l*16384 + (long)k*128 + j] = acc;
}

// ---------- ebW[l][j] = sum_d eb2[l][d]*NW1b[l][d][j] ----------
__global__ __launch_bounds__(128) void ebw_kernel(
    const void* __restrict__ eb2, const void* __restrict__ nw1,
    float* __restrict__ ebW, const int* __restrict__ flagp)
{
  const int isbf = *flagp;
  int l = blockIdx.x, j = threadIdx.x;
  long nb = (long)l*256*128 + 128*128;
  float acc = 0.f;
  for (int d=0; d<128; d++)
    acc += ldf(eb2, (long)l*128 + d, isbf) * ldf(nw1, nb + (long)d*128 + j, isbf);
  ebW[l*128+j] = acc;
}

// ---------- per-layer w2p = EW2 @ pw1[0:128], c2p = eb2 . pw1[0:128] ----------
__global__ __launch_bounds__(128) void w2p_kernel(
    const void* __restrict__ ew2, const void* __restrict__ eb2, const void* __restrict__ pw1,
    float* __restrict__ w2p, float* __restrict__ c2p, const int* __restrict__ flagp)
{
  const int isbf = *flagp;
  int l = blockIdx.x, i = threadIdx.x;
  long Woff = (long)l*128*128, poff = (long)l*129;
  float acc = 0.f;
  for (int j=0;j<128;j++) acc += ldf(ew2, Woff + (long)i*128 + j, isbf) * ldf(pw1, poff + j, isbf);
  w2p[l*128+i] = acc;
  __shared__ float red[128];
  red[i] = ldf(eb2, (long)l*128 + i, isbf) * ldf(pw1, poff + i, isbf);
  __syncthreads();
  for (int st=64; st>0; st>>=1){ if (i<st) red[i]+=red[i+st]; __syncthreads(); }
  if (i==0) c2p[l] = red[0];
}

__global__ void pparm_kernel(const void* pw1, const void* pb1, const void* pw2, const void* pb2,
                             float* pparm, const int* flagp)
{
  const int isbf = *flagp;
  int l = threadIdx.x;
  if (l < 4){
    pparm[l*4+0] = ldf(pw1, (long)l*129 + 128, isbf);
    pparm[l*4+1] = ldf(pb1, l, isbf);
    pparm[l*4+2] = ldf(pw2, l, isbf);
    pparm[l*4+3] = ldf(pb2, l, isbf);
  }
}

// ---------- CSR build: histogram, 3-stage scan, scatter ----------
__global__ __launch_bounds__(256) void hist_kernel(const int* __restrict__ tgt, int* __restrict__ cnt, int E){
  int i = blockIdx.x*256 + threadIdx.x;
  if (i < E) atomicAdd(&cnt[tgt[i]], 1);
}

__global__ __launch_bounds__(256) void bsum_kernel(const int* __restrict__ cnt, int* __restrict__ bsum, int N){
  int i = blockIdx.x*256 + threadIdx.x;
  int v = (i < N) ? cnt[i] : 0;
#pragma unroll
  for (int off=32; off; off>>=1) v += __shfl_down(v, off);
  __shared__ int ws[4];
  if ((threadIdx.x & 63) == 0) ws[threadIdx.x>>6] = v;
  __syncthreads();
  if (threadIdx.x == 0) bsum[blockIdx.x] = ws[0]+ws[1]+ws[2]+ws[3];
}

__global__ __launch_bounds__(256) void bscan_kernel(int* __restrict__ bsum, int nb){
  __shared__ int lds[256];
  int i = threadIdx.x;
  int v = (i < nb) ? bsum[i] : 0;
  lds[i] = v; __syncthreads();
#pragma unroll
  for (int off=1; off<256; off<<=1){
    int t = (i>=off)? lds[i-off] : 0; __syncthreads();
    lds[i] += t; __syncthreads();
  }
  if (i < nb) bsum[i] = lds[i] - v;  // exclusive prefix
}

__global__ __launch_bounds__(256) void csr_kernel(
    const int* __restrict__ cnt, const int* __restrict__ bsum,
    int* __restrict__ rowptr, int* __restrict__ cursor, float* __restrict__ degf, int N)
{
  __shared__ int lds[256];
  int i = blockIdx.x*256 + threadIdx.x;
  int c = (i < N) ? cnt[i] : 0;
  lds[threadIdx.x] = c; __syncthreads();
#pragma unroll
  for (int off=1; off<256; off<<=1){
    int t = (threadIdx.x>=off)? lds[threadIdx.x-off] : 0; __syncthreads();
    lds[threadIdx.x] += t; __syncthreads();
  }
  int run = bsum[blockIdx.x] + lds[threadIdx.x] - c;  // exclusive
  if (i < N){
    rowptr[i] = run; cursor[i] = run; degf[i] = (float)c;
    if (i == N-1) rowptr[N] = run + c;
  }
}

__global__ __launch_bounds__(256) void scatter_kernel(
    const int* __restrict__ src, const int* __restrict__ tgt,
    int* __restrict__ cursor, int* __restrict__ permsrc, int E)
{
  int e = blockIdx.x*256 + threadIdx.x;
  if (e >= E) return;
  int t = tgt[e];
  int p = atomicAdd(&cursor[t], 1);
  permsrc[p] = src[e];
}

// ---------- initial projection x = nf @ npw + npb (2 nodes/block) ----------
__global__ __launch_bounds__(256) void proj_kernel(
    const void* __restrict__ nf, const void* __restrict__ W, const void* __restrict__ bvec,
    float* __restrict__ xf, u16* __restrict__ xb, int N, const int* __restrict__ flagp)
{
  const int isbf = *flagp;
  int n = blockIdx.x*2 + (threadIdx.x>>7), d = threadIdx.x & 127;
  if (n >= N) return;
  float acc = ldf(bvec, d, isbf);
#pragma unroll
  for (int f=0; f<12; f++) acc += ldf(nf, (long)n*12+f, isbf) * ldf(W, f*128+d, isbf);
  xf[(long)n*128+d] = acc;
  xb[(long)n*128+d] = f2b(acc);
}

__global__ __launch_bounds__(256) void cvtp_kernel(const void* __restrict__ pos, float* __restrict__ pf,
                                                   int n, const int* __restrict__ flagp){
  const int isbf = *flagp;
  int i = blockIdx.x*256 + threadIdx.x;
  if (i < n) pf[i] = ldf(pos, i, isbf);
}

// ---------- streaming A/B matmul: Ab = bf16(x@Wa+eb1), Bb = bf16(x@Wb) ----------
// Weights staged in LDS once per block (64 KB dyn); grid-stride over 16-row tiles.
__global__ __launch_bounds__(256) void mm_ab_kernel(
    const u16* __restrict__ X, const u16* __restrict__ Wa, const u16* __restrict__ Wb,
    const void* __restrict__ bias, long bias_off,
    u16* __restrict__ Ab, u16* __restrict__ Bb, const int* __restrict__ flagp)
{
  extern __shared__ u16 wlds[];
  const int tid = threadIdx.x, wave = tid>>6, lane = tid&63;
  const int isbf = *flagp;
  const int lr = lane&15, lg = lane>>4;
  for (int i=tid; i<2048; i+=256){
    *(bf16x8*)(wlds + (long)i*8)          = *(const bf16x8*)(Wa + (long)i*8);
    *(bf16x8*)(wlds + 16384 + (long)i*8)  = *(const bf16x8*)(Wb + (long)i*8);
  }
  float biasv[8];
#pragma unroll
  for (int nt=0;nt<8;nt++) biasv[nt] = ldf(bias, bias_off + nt*16 + lr, isbf);
  __syncthreads();
  for (int tile = blockIdx.x*4 + wave; tile < NTILES; tile += MMGRID*4){
    const u16* xr = X + ((long)tile*16 + lr)*128;
    bf16x8 a[4];
#pragma unroll
    for (int kk=0;kk<4;kk++) a[kk] = *(const bf16x8*)(xr + kk*32 + lg*8);
    floatx4 accA[8], accB[8];
#pragma unroll
    for (int i=0;i<8;i++){ accA[i]=(floatx4){0,0,0,0}; accB[i]=(floatx4){0,0,0,0}; }
#pragma unroll
    for (int kk=0;kk<4;kk++){
#pragma unroll
      for (int nt=0;nt<8;nt++){
        bf16x8 ba = *(const bf16x8*)(wlds + ((kk*8+nt)*64 + lane)*8);
        accA[nt] = __builtin_amdgcn_mfma_f32_16x16x32_bf16(a[kk], ba, accA[nt], 0, 0, 0);
        bf16x8 bb = *(const bf16x8*)(wlds + 16384 + ((kk*8+nt)*64 + lane)*8);
        accB[nt] = __builtin_amdgcn_mfma_f32_16x16x32_bf16(a[kk], bb, accB[nt], 0, 0, 0);
      }
    }
#pragma unroll
    for (int r=0;r<4;r++){
      long row = (long)tile*16 + lg*4 + r;
#pragma unroll
      for (int nt=0;nt<8;nt++){
        int col = nt*16 + lr;
        Ab[row*128+col] = f2b(accA[nt][r] + biasv[nt]);
        Bb[row*128+col] = f2b(accB[nt][r]);
      }
    }
  }
}

// ---------- streaming hidden matmul: hb = bf16(silu(xb@NW1a + Hb@W12 + deg*ebW + nb1)) ----------
__global__ __launch_bounds__(256) void mm_hidden_kernel(
    const u16* __restrict__ X, const u16* __restrict__ H,
    const u16* __restrict__ W1, const u16* __restrict__ W2,
    const void* __restrict__ nb1, long nb1_off,
    const float* __restrict__ degf, const float* __restrict__ ebW,
    u16* __restrict__ hb, const int* __restrict__ flagp)
{
  extern __shared__ u16 wlds[];
  const int tid = threadIdx.x, wave = tid>>6, lane = tid&63;
  const int isbf = *flagp;
  const int lr = lane&15, lg = lane>>4;
  for (int i=tid; i<2048; i+=256){
    *(bf16x8*)(wlds + (long)i*8)          = *(const bf16x8*)(W1 + (long)i*8);
    *(bf16x8*)(wlds + 16384 + (long)i*8)  = *(const bf16x8*)(W2 + (long)i*8);
  }
  float nb1v[8], ebv[8];
#pragma unroll
  for (int nt=0;nt<8;nt++){ int col=nt*16+lr; nb1v[nt]=ldf(nb1, nb1_off+col, isbf); ebv[nt]=ebW[col]; }
  __syncthreads();
  for (int tile = blockIdx.x*4 + wave; tile < NTILES; tile += MMGRID*4){
    const u16* xr = X + ((long)tile*16 + lr)*128;
    const u16* hr = H + ((long)tile*16 + lr)*128;
    bf16x8 ax[4], ah[4];
#pragma unroll
    for (int kk=0;kk<4;kk++){
      ax[kk] = *(const bf16x8*)(xr + kk*32 + lg*8);
      ah[kk] = *(const bf16x8*)(hr + kk*32 + lg*8);
    }
    floatx4 acc[8];
#pragma unroll
    for (int i=0;i<8;i++) acc[i]=(floatx4){0,0,0,0};
#pragma unroll
    for (int kk=0;kk<4;kk++){
#pragma unroll
      for (int nt=0;nt<8;nt++){
        bf16x8 b1 = *(const bf16x8*)(wlds + ((kk*8+nt)*64 + lane)*8);
        acc[nt] = __builtin_amdgcn_mfma_f32_16x16x32_bf16(ax[kk], b1, acc[nt], 0, 0, 0);
        bf16x8 b2 = *(const bf16x8*)(wlds + 16384 + ((kk*8+nt)*64 + lane)*8);
        acc[nt] = __builtin_amdgcn_mfma_f32_16x16x32_bf16(ah[kk], b2, acc[nt], 0, 0, 0);
      }
    }
    float dv[4];
#pragma unroll
    for (int r=0;r<4;r++) dv[r] = degf[(long)tile*16 + lg*4 + r];
#pragma unroll
    for (int r=0;r<4;r++){
      long row = (long)tile*16 + lg*4 + r;
#pragma unroll
      for (int nt=0;nt<8;nt++){
        int col = nt*16 + lr;
        hb[row*128+col] = f2b(siluf(acc[nt][r] + nb1v[nt] + dv[r]*ebv[nt]));
      }
    }
  }
}

// ---------- streaming residual matmul: xnew = xf + hb@NW2 + nb2 ----------
// LN=0: writes xf (fp32) + xb (bf16).  LN=1: layernorm -> d_out, no x writes.
template<int LN>
__global__ __launch_bounds__(256) void mm_res_kernel(
    const u16* __restrict__ H, const u16* __restrict__ W,
    const void* __restrict__ nb2, long nb2_off,
    float* __restrict__ xf, u16* __restrict__ xb,
    const void* __restrict__ lng, const void* __restrict__ lnb, void* __restrict__ outp,
    const int* __restrict__ flagp)
{
  extern __shared__ u16 wlds[];
  const int tid = threadIdx.x, wave = tid>>6, lane = tid&63;
  const int isbf = *flagp;
  const int lr = lane&15, lg = lane>>4;
  for (int i=tid; i<2048; i+=256)
    *(bf16x8*)(wlds + (long)i*8) = *(const bf16x8*)(W + (long)i*8);
  float nb2v[8];
#pragma unroll
  for (int nt=0;nt<8;nt++) nb2v[nt] = ldf(nb2, nb2_off + nt*16 + lr, isbf);
  float gv[8], bvv[8];
  if (LN){
#pragma unroll
    for (int nt=0;nt<8;nt++){ int col=nt*16+lr; gv[nt]=ldf(lng,col,isbf); bvv[nt]=ldf(lnb,col,isbf); }
  }
  __syncthreads();
  for (int tile = blockIdx.x*4 + wave; tile < NTILES; tile += MMGRID*4){
    const u16* hr = H + ((long)tile*16 + lr)*128;
    bf16x8 a[4];
#pragma unroll
    for (int kk=0;kk<4;kk++) a[kk] = *(const bf16x8*)(hr + kk*32 + lg*8);
    floatx4 acc[8];
#pragma unroll
    for (int i=0;i<8;i++) acc[i]=(floatx4){0,0,0,0};
#pragma unroll
    for (int kk=0;kk<4;kk++){
#pragma unroll
      for (int nt=0;nt<8;nt++){
        bf16x8 b = *(const bf16x8*)(wlds + ((kk*8+nt)*64 + lane)*8);
        acc[nt] = __builtin_amdgcn_mfma_f32_16x16x32_bf16(a[kk], b, acc[nt], 0, 0, 0);
      }
    }
#pragma unroll
    for (int r=0;r<4;r++){
      long row = (long)tile*16 + lg*4 + r;
#pragma unroll
      for (int nt=0;nt<8;nt++){
        int col = nt*16 + lr;
        float v = acc[nt][r] + nb2v[nt] + xf[row*128+col];
        acc[nt][r] = v;
        if (!LN){ xf[row*128+col] = v; xb[row*128+col] = f2b(v); }
      }
    }
    if (LN){
      float s[4] = {0,0,0,0}, q[4] = {0,0,0,0};
#pragma unroll
      for (int r=0;r<4;r++){
#pragma unroll
        for (int nt=0;nt<8;nt++){ float v = acc[nt][r]; s[r] += v; q[r] += v*v; }
      }
#pragma unroll
      for (int mask=1; mask<16; mask<<=1){
#pragma unroll
        for (int r=0;r<4;r++){ s[r] += __shfl_xor(s[r], mask); q[r] += __shfl_xor(q[r], mask); }
      }
#pragma unroll
      for (int r=0;r<4;r++){
        long row = (long)tile*16 + lg*4 + r;
        float mu = s[r]*(1.f/128.f);
        float var = q[r]*(1.f/128.f) - mu*mu;
        float inv = rsqrtf(var + 1e-5f);
#pragma unroll
        for (int nt=0;nt<8;nt++){
          int col = nt*16 + lr;
          float y = (acc[nt][r]-mu)*inv*gv[nt] + bvv[nt];
          if (isbf) ((u16*)outp)[row*128+col] = f2b(y);
          else      ((float*)outp)[row*128+col] = y;
        }
      }
    }
  }
}

// ---------- CSR aggregation: one wave per target node, chunked x4 ----------
__global__ __launch_bounds__(256) void agg_kernel(
    const int* __restrict__ rowptr, const int* __restrict__ permsrc,
    const float* __restrict__ pf_in,
    const u16* __restrict__ A, const u16* __restrict__ B,
    const void* __restrict__ ew1, long w1c_off,
    const float* __restrict__ w2p, const float* __restrict__ c2pl,
    const float* __restrict__ pp,
    u16* __restrict__ Hb, float* __restrict__ pf_out, int N,
    const int* __restrict__ flagp)
{
  const int isbf = *flagp;
  int tid = threadIdx.x, lane = tid & 63;
  int t = blockIdx.x*4 + (tid>>6);
  if (t >= N) return;
  int tu = __builtin_amdgcn_readfirstlane(t);   // wave-uniform -> scalar loads
  float c0 = ldf(ew1, w1c_off + 2*lane,     isbf);
  float c1 = ldf(ew1, w1c_off + 2*lane + 1, isbf);
  float2 wp = *(const float2*)(w2p + 2*lane);
  float c2 = c2pl[0];
  float p0 = pp[0], p1 = pp[1], p2 = pp[2], p3 = pp[3];
  int jb = rowptr[tu], je = rowptr[tu+1];
  float2 pt = *(const float2*)(pf_in + 2*(long)tu);
  unsigned bv = *(const unsigned*)(B + (long)tu*128 + 2*lane);
  float b0 = b2f((u16)bv), b1 = b2f((u16)(bv>>16));
  float h0a = 0.f, h1a = 0.f, dpx = 0.f, dpy = 0.f;
  for (int j0 = jb; j0 < je; j0 += 4){
    int m = je - j0; if (m > 4) m = 4;
    int s[4]; float2 ps[4]; unsigned av[4];
    float part[4], dist[4], dxv[4], dyv[4];
#pragma unroll
    for (int c=0;c<4;c++) if (c<m) s[c] = permsrc[j0+c];
#pragma unroll
    for (int c=0;c<4;c++) if (c<m){
      ps[c] = *(const float2*)(pf_in + 2*(long)s[c]);
      av[c] = *(const unsigned*)(A + (long)s[c]*128 + 2*lane);
    }
#pragma unroll
    for (int c=0;c<4;c++){
      if (c<m){
        float dx = pt.x - ps[c].x, dy = pt.y - ps[c].y;
        float d2 = dx*dx + dy*dy;
        float dd = __builtin_amdgcn_sqrtf(d2);
        float h0 = siluf(b2f((u16)av[c])       + b0 + dd*c0);
        float h1 = siluf(b2f((u16)(av[c]>>16)) + b1 + dd*c1);
        h0a += h0; h1a += h1;
        part[c] = h0*wp.x + h1*wp.y;
        dist[c] = dd; dxv[c] = dx; dyv[c] = dy;
      } else part[c] = 0.f;
    }
#pragma unroll
    for (int off=32; off; off>>=1){
#pragma unroll
      for (int c=0;c<4;c++) part[c] += __shfl_xor(part[c], off);
    }
#pragma unroll
    for (int c=0;c<4;c++){
      if (c<m){
        float spre = part[c] + c2 + dist[c]*p0 + p1;
        float pwv  = siluf(spre)*p2 + p3;
        float inv  = __builtin_amdgcn_rcpf(dist[c] + 1e-6f);
        dpx += dxv[c]*inv*pwv; dpy += dyv[c]*inv*pwv;
      }
    }
  }
  *(unsigned*)(Hb + (long)tu*128 + 2*lane) = (unsigned)f2b(h0a) | ((unsigned)f2b(h1a)<<16);
  if (lane == 0){
    float2 o; o.x = pt.x + dpx; o.y = pt.y + dpy;
    *(float2*)(pf_out + 2*(long)tu) = o;
  }
}

extern "C" void kernel_launch(void* const* d_in, const int* in_sizes, int n_in,
                              void* d_out, int out_size, void* d_ws, size_t ws_size,
                              hipStream_t stream)
{
  const void* nf  = d_in[0];
  const void* pos = d_in[1];
  const void* npw = d_in[3];
  const void* npb = d_in[4];
  const void* ew1 = d_in[7];
  const void* eb1 = d_in[8];
  const void* ew2 = d_in[9];
  const void* eb2 = d_in[10];
  const void* nw1 = d_in[11];
  const void* nb1 = d_in[12];
  const void* nw2 = d_in[13];
  const void* nb2 = d_in[14];
  const void* pw1 = d_in[15];
  const void* pb1 = d_in[16];
  const void* pw2 = d_in[17];
  const void* pb2 = d_in[18];
  const void* lng = d_in[19];
  const void* lnb = d_in[20];
  const int* eidx = (const int*)d_in[21];
  const int N = NNODES, E = NEDGES;
  const int* srcp = eidx;
  const int* tgtp = eidx + E;

  char* w = (char*)d_ws;
  size_t off = 0;
  auto alloc = [&](size_t bytes)->char* { char* p = w + off; off += (bytes + 255)/256*256; return p; };
  float* xf    = (float*)alloc((size_t)N*128*4);
  u16*   xb    = (u16*)  alloc((size_t)N*128*2);
  u16*   Ab    = (u16*)  alloc((size_t)N*128*2);
  u16*   Bb    = (u16*)  alloc((size_t)N*128*2);
  u16*   Hb    = (u16*)  alloc((size_t)N*128*2);
  float* pf0   = (float*)alloc((size_t)N*2*4);
  float* pf1   = (float*)alloc((size_t)N*2*4);
  int*   cnt   = (int*)  alloc((size_t)N*4);
  int*   rowptr= (int*)  alloc((size_t)(N+1)*4);
  int*   cursor= (int*)  alloc((size_t)N*4);
  float* degf  = (float*)alloc((size_t)N*4);
  int*   perm  = (int*)  alloc((size_t)E*4);
  int*   bsum  = (int*)  alloc(256*4);
  u16*   pk    = (u16*)  alloc((size_t)28*16384*2);
  float* W12f  = (float*)alloc((size_t)4*16384*4);
  float* ebW   = (float*)alloc(4*128*4);
  float* w2p   = (float*)alloc(4*128*4);
  float* c2p   = (float*)alloc(4*4);
  float* pparm = (float*)alloc(16*4);
  int*   flag  = (int*)  alloc(4);
  u16* hb = Ab;   // Ab dead after agg_kernel; rewritten by next mm_ab

  const int NB = (N + 255)/256;  // 196 <= 256
  detect_kernel<<<1, 64, 0, stream>>>(lng, flag);
  hipMemsetAsync(cnt, 0, (size_t)N*4, stream);
  hist_kernel<<<(E+255)/256, 256, 0, stream>>>(tgtp, cnt, E);
  bsum_kernel<<<NB, 256, 0, stream>>>(cnt, bsum, N);
  bscan_kernel<<<1, 256, 0, stream>>>(bsum, NB);
  csr_kernel<<<NB, 256, 0, stream>>>(cnt, bsum, rowptr, cursor, degf, N);
  scatter_kernel<<<(E+255)/256, 256, 0, stream>>>(srcp, tgtp, cursor, perm, E);
  pack_kernel<<<192, 256, 0, stream>>>(ew1, ew2, nw1, nw2, pk, flag);
  w12_kernel<<<512, 128, 0, stream>>>(ew2, nw1, W12f, flag);
  ebw_kernel<<<4, 128, 0, stream>>>(eb2, nw1, ebW, flag);
  pack2_kernel<<<32, 256, 0, stream>>>(W12f, pk);
  w2p_kernel<<<4, 128, 0, stream>>>(ew2, eb2, pw1, w2p, c2p, flag);
  pparm_kernel<<<1, 64, 0, stream>>>(pw1, pb1, pw2, pb2, pparm, flag);
  proj_kernel<<<(N+1)/2, 256, 0, stream>>>(nf, npw, npb, xf, xb, N, flag);
  cvtp_kernel<<<(2*N+255)/256, 256, 0, stream>>>(pos, pf0, 2*N, flag);

  // layer 0 A/B from projected x
  mm_ab_kernel<<<MMGRID, 256, 65536, stream>>>(xb, pk + 0*16384, pk + 1*16384,
                                               eb1, 0, Ab, Bb, flag);
  for (int l = 0; l < 4; l++){
    const u16* NW1a = pk + (l*6+3)*16384;
    const u16* NW2p = pk + (l*6+5)*16384;
    const u16* W12p = pk + (24+l)*16384;
    float* pin  = (l & 1) ? pf1 : pf0;
    float* pout = (l & 1) ? pf0 : pf1;

    agg_kernel<<<(N+3)/4, 256, 0, stream>>>(
        rowptr, perm, pin, Ab, Bb,
        ew1, (long)l*257*128 + 256*128,
        w2p + l*128, c2p + l, pparm + l*4,
        Hb, pout, N, flag);
    mm_hidden_kernel<<<MMGRID, 256, 65536, stream>>>(
        xb, Hb, NW1a, W12p, nb1, (long)l*128, degf, ebW + l*128, hb, flag);
    if (l < 3){
      mm_res_kernel<0><<<MMGRID, 256, 32768, stream>>>(
          hb, NW2p, nb2, (long)l*128, xf, xb, nullptr, nullptr, nullptr, flag);
      mm_ab_kernel<<<MMGRID, 256, 65536, stream>>>(
          xb, pk + ((l+1)*6+0)*16384, pk + ((l+1)*6+1)*16384,
          eb1, (long)(l+1)*128, Ab, Bb, flag);
    } else {
      mm_res_kernel<1><<<MMGRID, 256, 32768, stream>>>(
          hb, NW2p, nb2, (long)l*128, xf, nullptr, lng, lnb, d_out, flag);
    }
  }
}